// Round 1
// baseline (215.599 us; speedup 1.0000x reference)
//
#include <hip/hip_runtime.h>
#include <math.h>

#define NROWS 16384
#define INDIM 2048
#define NE 16
#define NW 16
#define KC (INDIM / NW)   // 128 k per wave

__global__ __launch_bounds__(1024) void gate_kernel(
    const float* __restrict__ x,
    const float* __restrict__ W1,
    const float* __restrict__ W2,
    float* __restrict__ out)
{
    // part: pair-preadded partials (waves 8..15 add into waves 0..7's slots)
    __shared__ float part[NW / 2][64][17];   // 34816 B (pad 17 -> conflict-free)
    __shared__ float hbuf[64][17];           //  4352 B
    __shared__ float w2s[NE * NE];           //  1024 B   total < 64 KB

    const int tid  = threadIdx.x;
    const int lane = tid & 63;
    const int wv   = __builtin_amdgcn_readfirstlane(tid >> 6);  // wave-uniform k-slice id
    const int row0 = blockIdx.x * 64;

    if (tid < 64) {  // stage W2 once (256 floats)
        ((float4*)w2s)[tid] = ((const float4*)W2)[tid];
    }

    // ---- phase 1: per-wave partial dot products over its 128-wide k-slice ----
    float acc[NE];
    #pragma unroll
    for (int e = 0; e < NE; ++e) acc[e] = 0.0f;
    {
        const int    row = row0 + lane;
        const float* xr  = x + (size_t)row * INDIM + wv * KC;
        const float* w1  = W1 + wv * KC;   // + e*INDIM + k ; wave-uniform -> s_load

        #pragma unroll 2
        for (int s = 0; s < KC / 4; ++s) {
            const float4 xv = *(const float4*)(xr + 4 * s);
            #pragma unroll
            for (int e = 0; e < NE; ++e) {
                const float* we = w1 + e * INDIM + 4 * s;
                float a = acc[e];
                a = fmaf(xv.x, we[0], a);
                a = fmaf(xv.y, we[1], a);
                a = fmaf(xv.z, we[2], a);
                a = fmaf(xv.w, we[3], a);
                acc[e] = a;
            }
        }
    }
    if (wv < NW / 2) {
        #pragma unroll
        for (int e = 0; e < NE; ++e) part[wv][lane][e] = acc[e];
    }
    __syncthreads();
    if (wv >= NW / 2) {
        #pragma unroll
        for (int e = 0; e < NE; ++e) part[wv - NW / 2][lane][e] += acc[e];
    }
    __syncthreads();

    // ---- phase 2: reduce 8 pre-added partials + tanh -> hbuf ----
    {
        const int r = tid >> 4;
        const int e = tid & 15;
        float s = 0.0f;
        #pragma unroll
        for (int w = 0; w < NW / 2; ++w) s += part[w][r][e];
        hbuf[r][e] = tanhf(s);
    }
    __syncthreads();

    // ---- phase 3: per-row logits, sort, softmax, k policy, outputs ----
    if (tid < 64) {
        const int r   = tid;
        const int row = row0 + r;

        float hr[NE];
        #pragma unroll
        for (int e = 0; e < NE; ++e) hr[e] = hbuf[r][e];

        float v[NE];
        int   idx[NE];
        #pragma unroll
        for (int f = 0; f < NE; ++f) {
            float s = 0.0f;
            #pragma unroll
            for (int j = 0; j < 4; ++j) {
                const float4 w = ((const float4*)w2s)[f * 4 + j];
                s = fmaf(hr[4 * j + 0], w.x, s);
                s = fmaf(hr[4 * j + 1], w.y, s);
                s = fmaf(hr[4 * j + 2], w.z, s);
                s = fmaf(hr[4 * j + 3], w.w, s);
            }
            v[f]   = s / 0.7f;   // logits
            idx[f] = f;
        }

        // bitonic sort, ascending in key (-value, index) == stable descending argsort
        #pragma unroll
        for (int ksz = 2; ksz <= 16; ksz <<= 1) {
            #pragma unroll
            for (int jsz = ksz >> 1; jsz >= 1; jsz >>= 1) {
                #pragma unroll
                for (int i = 0; i < 16; ++i) {
                    const int l = i ^ jsz;
                    if (l > i) {
                        const bool asc   = ((i & ksz) == 0);
                        const bool keyGt = (v[i] < v[l]) ||
                                           (v[i] == v[l] && idx[i] > idx[l]);
                        if (keyGt == asc) {
                            float tv = v[i]; v[i] = v[l]; v[l] = tv;
                            int   ti = idx[i]; idx[i] = idx[l]; idx[l] = ti;
                        }
                    }
                }
            }
        }

        // softmax over sorted logits
        float p[NE];
        float tot = 0.0f;
        #pragma unroll
        for (int i = 0; i < NE; ++i) { p[i] = expf(v[i] - v[0]); tot += p[i]; }
        #pragma unroll
        for (int i = 0; i < NE; ++i) p[i] = p[i] / tot;

        float cum[NE];
        cum[0] = p[0];
        #pragma unroll
        for (int i = 1; i < NE; ++i) cum[i] = cum[i - 1] + p[i];

        int k = NE;  // fallback: idx_first = E-1 -> k = 16 (then clipped)
        #pragma unroll
        for (int i = NE - 1; i >= 0; --i) if (cum[i] >= 0.92f) k = i + 1;

        if ((p[0] >= 0.46f) && ((p[0] - p[1]) >= 0.1f)) k = 1;
        if ((k > 2) && ((cum[1] >= 0.82f) || (p[2] <= 0.12f) || ((p[1] - p[2]) <= 0.03f)))
            k = 2;
        k = k < 1 ? 1 : (k > 3 ? 3 : k);

        const float4 o0 = make_float4((float)idx[0], (float)idx[1], (float)idx[2], (float)idx[3]);
        const float4 o1 = make_float4((float)idx[4], (float)idx[5], (float)idx[6], (float)idx[7]);
        const float4 s0 = make_float4(k > 0 ? p[0] : 0.0f, k > 1 ? p[1] : 0.0f,
                                      k > 2 ? p[2] : 0.0f, k > 3 ? p[3] : 0.0f);
        const float4 s1 = make_float4(k > 4 ? p[4] : 0.0f, k > 5 ? p[5] : 0.0f,
                                      k > 6 ? p[6] : 0.0f, k > 7 ? p[7] : 0.0f);
        const float4 m0 = make_float4(k > 0 ? 1.0f : 0.0f, k > 1 ? 1.0f : 0.0f,
                                      k > 2 ? 1.0f : 0.0f, k > 3 ? 1.0f : 0.0f);
        const float4 m1 = make_float4(k > 4 ? 1.0f : 0.0f, k > 5 ? 1.0f : 0.0f,
                                      k > 6 ? 1.0f : 0.0f, k > 7 ? 1.0f : 0.0f);

        float4* oI = (float4*)(out + (size_t)row * 8);
        float4* oS = (float4*)(out + (size_t)NROWS * 8  + (size_t)row * 8);
        float4* oM = (float4*)(out + (size_t)NROWS * 16 + (size_t)row * 8);
        oI[0] = o0; oI[1] = o1;
        oS[0] = s0; oS[1] = s1;
        oM[0] = m0; oM[1] = m1;
        out[(size_t)NROWS * 24 + row] = (float)k;
    }
}

extern "C" void kernel_launch(void* const* d_in, const int* in_sizes, int n_in,
                              void* d_out, int out_size, void* d_ws, size_t ws_size,
                              hipStream_t stream)
{
    const float* x  = (const float*)d_in[0];
    const float* W1 = (const float*)d_in[1];
    const float* W2 = (const float*)d_in[2];
    gate_kernel<<<NROWS / 64, 1024, 0, stream>>>(x, W1, W2, (float*)d_out);
}